// Round 1
// baseline (168.514 us; speedup 1.0000x reference)
//
#include <hip/hip_runtime.h>

#define VOCAB 1024
#define MAXC  4    // max backoff-chain length (MAX_ORDER)
#define MAXK  16   // padded arcs-per-state slot (actual K = 10)

__global__ __launch_bounds__(256)
void ngram_advance(const float* __restrict__ arcs_weights,
                   const float* __restrict__ backoff_weights,
                   const int*   __restrict__ to_states,
                   const int*   __restrict__ ilabels,
                   const int*   __restrict__ backoff_to_states,
                   const int*   __restrict__ state_start_arcs,
                   const int*   __restrict__ state_end_arcs,
                   const int*   __restrict__ states,
                   float* __restrict__ out_scores,
                   float* __restrict__ out_next)
{
    __shared__ int   ch_state[MAXC];
    __shared__ int   ch_sa[MAXC];
    __shared__ int   ch_na[MAXC];
    __shared__ float ch_bw[MAXC];
    __shared__ int   ch_len;
    __shared__ int   s_lab[MAXC][MAXK];
    __shared__ float s_wt [MAXC][MAXK];
    __shared__ int   s_to [MAXC][MAXK];

    const int b   = blockIdx.x;
    const int tid = threadIdx.x;

    // --- thread 0: walk the (per-row, label-independent) backoff chain ---
    if (tid == 0) {
        int cur = states[b];
        int len = 0;
        for (;;) {
            int sa = state_start_arcs[cur];
            ch_state[len] = cur;
            ch_sa[len]    = sa;
            ch_na[len]    = state_end_arcs[cur] - sa;
            ch_bw[len]    = backoff_weights[cur];
            ++len;
            if (cur == 0 || len == MAXC) break;   // state 0 always resolves every label
            cur = backoff_to_states[cur];
        }
        ch_len = len;
    }
    __syncthreads();

    const int len = ch_len;

    // --- stage non-start chain states' arcs (K<=10 each) into LDS ---
    for (int idx = tid; idx < MAXC * MAXK; idx += blockDim.x) {
        int l = idx / MAXK, j = idx % MAXK;
        if (l < len && ch_state[l] != 0 && j < ch_na[l]) {
            int a = ch_sa[l] + j;
            s_lab[l][j] = ilabels[a];
            s_wt [l][j] = arcs_weights[a];
            s_to [l][j] = to_states[a];
        }
    }
    __syncthreads();

    // --- per label: predicated scan down the chain ---
    const long long obase = (long long)b * VOCAB;
    for (int v = tid; v < VOCAB; v += blockDim.x) {
        float score = 0.f;
        int   nxt   = 0;
        bool  done  = false;
        for (int l = 0; l < len && !done; ++l) {
            if (ch_state[l] == 0) {
                // start state: ilabels are arange(V) -> direct, coalesced index
                int a = ch_sa[l] + v;
                score += arcs_weights[a];
                nxt    = to_states[a];
                done   = true;
            } else {
                int  na    = ch_na[l];
                bool found = false;
                for (int j = 0; j < na; ++j) {   // <=10 LDS broadcasts, conflict-free
                    if (s_lab[l][j] == v) {
                        score += s_wt[l][j];
                        nxt    = s_to[l][j];
                        found  = true;
                    }
                }
                if (found) done = true;
                else       score += ch_bw[l];    // same accumulation order as reference
            }
        }
        out_scores[obase + v] = score;
        out_next[obase + v]   = (float)nxt;      // state id < 2^24: exact in fp32
    }
}

extern "C" void kernel_launch(void* const* d_in, const int* in_sizes, int n_in,
                              void* d_out, int out_size, void* d_ws, size_t ws_size,
                              hipStream_t stream) {
    // setup_inputs() order:
    // 0 arcs_weights(f32) 1 backoff_weights(f32) 2 from_states(i32) 3 to_states(i32)
    // 4 ilabels(i32) 5 backoff_to_states(i32) 6 state_start_arcs(i32)
    // 7 state_end_arcs(i32) 8 state_order(i32) 9 states(i32)
    const float* arcs_weights    = (const float*)d_in[0];
    const float* backoff_weights = (const float*)d_in[1];
    const int*   to_states       = (const int*)d_in[3];
    const int*   ilabels         = (const int*)d_in[4];
    const int*   backoff_to      = (const int*)d_in[5];
    const int*   ssa             = (const int*)d_in[6];
    const int*   sea             = (const int*)d_in[7];
    const int*   states          = (const int*)d_in[9];
    const int B = in_sizes[9];

    float* out_scores = (float*)d_out;
    float* out_next   = out_scores + (size_t)B * VOCAB;

    ngram_advance<<<dim3(B), dim3(256), 0, stream>>>(
        arcs_weights, backoff_weights, to_states, ilabels, backoff_to,
        ssa, sea, states, out_scores, out_next);
}

// Round 2
// 156.887 us; speedup vs baseline: 1.0741x; 1.0741x over previous
//
#include <hip/hip_runtime.h>

#define VOCAB 1024
#define MAXC  4      // max backoff-chain length (MAX_ORDER); chain always ends at state 0
#define SLOT_SHIFT 8

__global__ __launch_bounds__(256)
void ngram_advance(const float* __restrict__ arcs_weights,
                   const float* __restrict__ backoff_weights,
                   const int*   __restrict__ to_states,
                   const int*   __restrict__ ilabels,
                   const int*   __restrict__ backoff_to_states,
                   const int*   __restrict__ state_start_arcs,
                   const int*   __restrict__ state_end_arcs,
                   const int*   __restrict__ states,
                   float* __restrict__ out_scores,
                   float* __restrict__ out_next)
{
    // Per-label override table: (level<<8)|slot, sentinel = INT_MAX.
    __shared__ int   tab[VOCAB];
    __shared__ float s_wt[64];            // staged arc weights, slot = l*16+j
    __shared__ int   s_to[64];            // staged arc targets
    __shared__ int   ch_state[MAXC], ch_sa[MAXC], ch_na[MAXC];
    __shared__ float ch_bwsum[MAXC];      // prefix sums of backoff weights (chain order)
    __shared__ int   ch_len;

    const int b   = blockIdx.x;
    const int tid = threadIdx.x;

    // init override table (sentinel)
    for (int v = tid; v < VOCAB; v += 256) tab[v] = 0x7FFFFFFF;

    // thread 0: walk the per-row, label-independent backoff chain.
    // Orders strictly decrease along the chain, so it always terminates at
    // state 0 within MAXC steps; state 0's arcs are exactly arange(V).
    if (tid == 0) {
        int cur = states[b];
        int len = 0;
        float acc = 0.f;
        for (;;) {
            int sa = state_start_arcs[cur];
            ch_state[len] = cur;
            ch_sa[len]    = sa;
            ch_na[len]    = state_end_arcs[cur] - sa;
            ch_bwsum[len] = acc;                    // sum of bw over levels < len
            acc += backoff_weights[cur];            // chain-order accumulation == reference
            ++len;
            if (cur == 0 || len == MAXC) break;
            cur = backoff_to_states[cur];
        }
        ch_len = len;
    }
    __syncthreads();

    const int len = ch_len;

    // Scatter the <=30 non-start arcs into the label table.
    // atomicMin keeps the EARLIEST level (reference: first found wins).
    // Labels are strictly increasing within a level -> no intra-level dups.
    if (tid < 64) {
        int l = tid >> 4, j = tid & 15;
        if (l < len && ch_state[l] != 0 && j < ch_na[l]) {
            int a = ch_sa[l] + j;
            s_wt[tid] = arcs_weights[a];
            s_to[tid] = to_states[a];
            atomicMin(&tab[ilabels[a]], (l << SLOT_SHIFT) | tid);
        }
    }
    __syncthreads();

    // O(1) per-label gather. Non-start hits: prefix-bw + staged wt/to.
    // Fallback (>=994 of 1024 labels): state 0 always matches; its arc index
    // is simply sa0 + v (coalesced; same 8 KB for every block -> L2-hot).
    const int    last   = len - 1;          // chain's last level is state 0
    const float  bwlast = ch_bwsum[last];
    const int    sa0    = ch_sa[last];
    const size_t obase  = (size_t)b * VOCAB;
    for (int v = tid; v < VOCAB; v += 256) {
        int   t  = tab[v];
        int   fl = t >> SLOT_SHIFT;         // sentinel -> huge -> fallback
        float sc;
        int   nx;
        if (fl < last) {
            int slot = t & 255;
            sc = ch_bwsum[fl] + s_wt[slot];
            nx = s_to[slot];
        } else {
            sc = bwlast + arcs_weights[sa0 + v];
            nx = to_states[sa0 + v];
        }
        out_scores[obase + v] = sc;
        out_next[obase + v]   = (float)nx;   // state id < 2^24: exact in fp32
    }
}

extern "C" void kernel_launch(void* const* d_in, const int* in_sizes, int n_in,
                              void* d_out, int out_size, void* d_ws, size_t ws_size,
                              hipStream_t stream) {
    // setup_inputs() order:
    // 0 arcs_weights(f32) 1 backoff_weights(f32) 2 from_states(i32) 3 to_states(i32)
    // 4 ilabels(i32) 5 backoff_to_states(i32) 6 state_start_arcs(i32)
    // 7 state_end_arcs(i32) 8 state_order(i32) 9 states(i32)
    const float* arcs_weights    = (const float*)d_in[0];
    const float* backoff_weights = (const float*)d_in[1];
    const int*   to_states       = (const int*)d_in[3];
    const int*   ilabels         = (const int*)d_in[4];
    const int*   backoff_to      = (const int*)d_in[5];
    const int*   ssa             = (const int*)d_in[6];
    const int*   sea             = (const int*)d_in[7];
    const int*   states          = (const int*)d_in[9];
    const int B = in_sizes[9];

    float* out_scores = (float*)d_out;
    float* out_next   = out_scores + (size_t)B * VOCAB;

    ngram_advance<<<dim3(B), dim3(256), 0, stream>>>(
        arcs_weights, backoff_weights, to_states, ilabels, backoff_to,
        ssa, sea, states, out_scores, out_next);
}